// Round 16
// baseline (635.555 us; speedup 1.0000x reference)
//
#include <hip/hip_runtime.h>
#include <hip/hip_cooperative_groups.h>
#include <stdint.h>

// Problem dims (fixed by reference)
#define TOKENS 8192
#define DIN    4096
#define DOUT   4096

typedef short bf16x8 __attribute__((ext_vector_type(8)));  // 8 bf16 = 4 VGPRs
typedef float f32x4  __attribute__((ext_vector_type(4)));  // MFMA 16x16 accum
typedef int   i32x4  __attribute__((ext_vector_type(4)));  // NT-loadable int4
typedef float f32x4v __attribute__((ext_vector_type(4)));  // NT-loadable float4

// ---- fp32 -> bf16 round-to-nearest-even (inputs finite) ----
__device__ __forceinline__ unsigned short f2bf(float f) {
    union { float f; unsigned int u; } v; v.f = f;
    return (unsigned short)((v.u + 0x7fffu + ((v.u >> 16) & 1u)) >> 16);
}

// ---- ternary int {-1,0,1} -> bf16 bit pattern (2 selects, no float math) ----
__device__ __forceinline__ unsigned short tern2bf(int v) {
    return v == 0 ? (unsigned short)0u
                  : (v > 0 ? (unsigned short)0x3F80u : (unsigned short)0xBF80u);
}

// ---- async global->LDS, 16B/lane; LDS dest = wave-uniform base + lane*16 ----
__device__ __forceinline__ void gload_lds16(const unsigned short* g, unsigned short* l) {
    __builtin_amdgcn_global_load_lds(
        (const __attribute__((address_space(1))) unsigned int*)g,
        (__attribute__((address_space(3))) unsigned int*)l,
        16, 0, 0);
}

// ================= R16: single cooperative kernel =================
// Phase 1 (all 256 blocks x 512 thr = 131072 threads): convert x (f32->bf16,
// 4.19M 16B-chunks, 32/thread) and W (int32 [K][N] -> bf16 Wt [N][K], 8kx4n
// register-transpose units, 4/thread) with pure coalesced streaming.
// __threadfence (device-scope release: writers' L2 flush) + grid.sync, then
// Phase 2: R13-verified gemm, 2 rounds/block (wg and wg+256; 1 block/CU due to
// 128KB LDS so 256 blocks are exactly co-resident -> cooperative legal).
#define BM 256
#define BN 256
#define BK 64

#define STAGE_A(bufi, h, kt)                                                \
    do {                                                                    \
        gload_lds16(gA + (size_t)((h) * 128) * DIN + (kt),                  \
                    &sA[bufi][(h) * 8192 + wave * 1024]);                   \
        gload_lds16(gA + (size_t)((h) * 128 + 8) * DIN + (kt),              \
                    &sA[bufi][(h) * 8192 + wave * 1024 + 512]);             \
    } while (0)

#define STAGE_B(bufi, h, kt)                                                \
    do {                                                                    \
        gload_lds16(gB + (size_t)((h) * 128) * DIN + (kt),                  \
                    &sB[bufi][(h) * 8192 + wave * 1024]);                   \
        gload_lds16(gB + (size_t)((h) * 128 + 8) * DIN + (kt),              \
                    &sB[bufi][(h) * 8192 + wave * 1024 + 512]);             \
    } while (0)

#define BAR  __builtin_amdgcn_s_barrier()
#define SB0  __builtin_amdgcn_sched_barrier(0)
#define VM4  asm volatile("s_waitcnt vmcnt(4)" ::: "memory")
#define VM2  asm volatile("s_waitcnt vmcnt(2)" ::: "memory")
#define VM0  asm volatile("s_waitcnt vmcnt(0)" ::: "memory")
#define LGK4 asm volatile("s_waitcnt lgkmcnt(4)" ::: "memory")
#define LGK0 asm volatile("s_waitcnt lgkmcnt(0)" ::: "memory")

// 8 ds_read_b128: all B-frags of LDS buffer BUF (resident across 4 phases)
#define RD_B(BUF)                                                           \
    do {                                                                    \
        _Pragma("unroll") for (int ni = 0; ni < 4; ++ni) {                  \
            bfr[ni][0] = *(const bf16x8*)&sB[BUF][rowB + ni * 1024 + q80];  \
            bfr[ni][1] = *(const bf16x8*)&sB[BUF][rowB + ni * 1024 + q81];  \
        }                                                                   \
    } while (0)

// 4 ds_read_b128: A-frags, quadrant QD of buffer BUF -> register set AF
#define RD_A(AF, BUF, QD)                                                   \
    do {                                                                    \
        _Pragma("unroll") for (int m2 = 0; m2 < 2; ++m2) {                  \
            AF[m2][0] =                                                     \
                *(const bf16x8*)&sA[BUF][rowA + ((QD)*2 + m2) * 1024 + q80];\
            AF[m2][1] =                                                     \
                *(const bf16x8*)&sA[BUF][rowA + ((QD)*2 + m2) * 1024 + q81];\
        }                                                                   \
    } while (0)

// 16 MFMA: quadrant QD from A-set AF + resident bfr
#define MM(AF, QD)                                                          \
    do {                                                                    \
        __builtin_amdgcn_s_setprio(1);                                      \
        _Pragma("unroll") for (int ks = 0; ks < 2; ++ks)                    \
            _Pragma("unroll") for (int m2 = 0; m2 < 2; ++m2)                \
                _Pragma("unroll") for (int ni = 0; ni < 4; ++ni)            \
                    acc[(QD)*2 + m2][ni] =                                  \
                        __builtin_amdgcn_mfma_f32_16x16x32_bf16(            \
                            AF[m2][ks], bfr[ni][ks],                        \
                            acc[(QD)*2 + m2][ni], 0, 0, 0);                 \
        __builtin_amdgcn_s_setprio(0);                                      \
    } while (0)

__global__ __launch_bounds__(512, 1) void gemm_fused(
    const float* __restrict__ x, const int* __restrict__ W,
    unsigned short* __restrict__ xb, unsigned short* __restrict__ Wt,
    float* __restrict__ C) {
    const int K = DIN, N = DOUT;

    __shared__ __align__(16) unsigned short sA[2][BM * BK];  // 2 x 32 KB
    __shared__ __align__(16) unsigned short sB[2][BN * BK];  // 2 x 32 KB

    const int tid  = threadIdx.x;
    const int gtid = blockIdx.x * 512 + tid;       // 131072 threads

    // ================= phase 1: conversions (pure streaming) =================
    {
        // ---- x: f32 -> bf16, 32 chunks of 8 floats per thread ----
        const f32x4v* x4 = (const f32x4v*)x;
        uint4* o = (uint4*)xb;
        int c = gtid;
#pragma unroll 8
        for (int j = 0; j < 32; ++j, c += 131072) {
            f32x4v a = __builtin_nontemporal_load(&x4[2 * c]);
            f32x4v b2 = __builtin_nontemporal_load(&x4[2 * c + 1]);
            uint4 p;
            p.x = (unsigned)f2bf(a.x)  | ((unsigned)f2bf(a.y) << 16);
            p.y = (unsigned)f2bf(a.z)  | ((unsigned)f2bf(a.w) << 16);
            p.z = (unsigned)f2bf(b2.x) | ((unsigned)f2bf(b2.y) << 16);
            p.w = (unsigned)f2bf(b2.z) | ((unsigned)f2bf(b2.w) << 16);
            o[c] = p;                  // plain store: xb is read soon (L2/L3)
        }
        // ---- W: [K][N] int32 -> Wt [N][K] bf16, 8k x 4n units, 4/thread ----
#pragma unroll
        for (int j = 0; j < 4; ++j) {
            const int u   = gtid + j * 131072;
            const int n4  = u & 1023;          // n-quad index (read-coalesced)
            const int oct = u >> 10;           // k-octet 0..511
            const int kb  = oct * 8;
            i32x4 v[8];
#pragma unroll
            for (int r = 0; r < 8; ++r)
                v[r] = __builtin_nontemporal_load(
                    (const i32x4*)&W[(size_t)(kb + r) * DOUT + n4 * 4]);
#pragma unroll
            for (int jj = 0; jj < 4; ++jj) {
                uint4 p;
                p.x = (unsigned)tern2bf(v[0][jj]) | ((unsigned)tern2bf(v[1][jj]) << 16);
                p.y = (unsigned)tern2bf(v[2][jj]) | ((unsigned)tern2bf(v[3][jj]) << 16);
                p.z = (unsigned)tern2bf(v[4][jj]) | ((unsigned)tern2bf(v[5][jj]) << 16);
                p.w = (unsigned)tern2bf(v[6][jj]) | ((unsigned)tern2bf(v[7][jj]) << 16);
                *(uint4*)&Wt[(size_t)(n4 * 4 + jj) * DIN + kb] = p;  // plain store
            }
        }
    }
    __threadfence();                       // device-scope release (L2 flush)
    cooperative_groups::this_grid().sync();

    // ================= phase 2: R13 gemm, 2 rounds per block =================
    const int wave = tid >> 6;
    const int lane = tid & 63;
    const int wm = wave >> 2;               // 0..1  (M)
    const int wn = wave & 3;                // 0..3  (N)

    const int lrow = lane >> 3;             // staging row within 8-row chunk
    const int qsrc = (lane & 7) ^ lrow;     // pre-swizzled global k-quad

    const int mrow = lane & 15;
    const int kgrp = lane >> 4;
    const int xr   = lane & 7;
    const int q80  = ((kgrp ^ xr) << 3);
    const int q81  = (((4 | kgrp) ^ xr) << 3);
    const int rowA = (wm * 128 + mrow) << 6;
    const int rowB = (wn * 64 + mrow) << 6;

#pragma unroll 1
    for (int round = 0; round < 2; ++round) {
        const int wg  = blockIdx.x + (round << 8);         // bijective over 512
        const int xcd = wg & 7;
        const int idx = wg >> 3;
        const int bx  = (xcd & 1) * 8 + (idx & 7);         // 0..15
        const int by  = (xcd >> 1) * 8 + (idx >> 3);       // 0..31

        const unsigned short* gA =
            xb + (size_t)(by * BM + wave * 16 + lrow) * K + qsrc * 8;
        const unsigned short* gB =
            Wt + (size_t)(bx * BN + wave * 16 + lrow) * K + qsrc * 8;

        f32x4 acc[8][4];
#pragma unroll
        for (int i = 0; i < 8; ++i)
#pragma unroll
            for (int j = 0; j < 4; ++j) {
                f32x4 z = {0.f, 0.f, 0.f, 0.f};
                acc[i][j] = z;
            }
        bf16x8 bfr[4][2];
        bf16x8 afA[2][2];
        bf16x8 afB[2][2];

        BAR;              // round separation (WAR belt before re-staging)

        // ---- prologue: A0, B0, B1; VM4 confirms A0,B0; B1 flies ----
        STAGE_A(0, 0, 0);
        STAGE_A(0, 1, 0);
        STAGE_B(0, 0, 0);
        STAGE_B(0, 1, 0);
        STAGE_B(1, 0, 64);
        STAGE_B(1, 1, 64);
        VM4;
        BAR;
        RD_A(afA, 0, 0);

        // ---- main loop: 31 iters (tiles 0..61), 8 phases, 1 barrier each ----
        for (int kt = 0; kt + 256 <= K; kt += 128) {
            RD_B(0); SB0; RD_A(afB, 0, 1);
            STAGE_A(1, 0, kt + 64);
            BAR; LGK4; SB0; MM(afA, 0);

            RD_A(afA, 0, 2);
            STAGE_A(1, 1, kt + 64);
            BAR; LGK4; SB0; MM(afB, 1);

            RD_A(afB, 0, 3);
            STAGE_B(0, 0, kt + 128);
            VM2;
            BAR; LGK4; SB0; MM(afA, 2);

            RD_A(afA, 1, 0);
            STAGE_B(0, 1, kt + 128);
            BAR; LGK4; SB0; MM(afB, 3);

            RD_B(1); SB0; RD_A(afB, 1, 1);
            STAGE_A(0, 0, kt + 128);
            BAR; LGK4; SB0; MM(afA, 0);

            RD_A(afA, 1, 2);
            STAGE_A(0, 1, kt + 128);
            BAR; LGK4; SB0; MM(afB, 1);

            RD_A(afB, 1, 3);
            STAGE_B(1, 0, kt + 192);
            VM2;
            BAR; LGK4; SB0; MM(afA, 2);

            RD_A(afA, 0, 0);
            STAGE_B(1, 1, kt + 192);
            BAR; LGK4; SB0; MM(afB, 3);
        }

        // ---- peeled tail: tiles 62 (buf0) and 63 (buf1) ----
        {
            RD_B(0); SB0; RD_A(afB, 0, 1);
            STAGE_A(1, 0, K - 64);
            BAR; LGK4; SB0; MM(afA, 0);

            RD_A(afA, 0, 2);
            STAGE_A(1, 1, K - 64);
            BAR; LGK4; SB0; MM(afB, 1);

            RD_A(afB, 0, 3);
            VM0;
            BAR; LGK4; SB0; MM(afA, 2);

            RD_A(afA, 1, 0);
            BAR; LGK4; SB0; MM(afB, 3);

            RD_B(1); SB0; RD_A(afB, 1, 1);
            BAR; LGK4; SB0; MM(afA, 0);

            RD_A(afA, 1, 2);
            BAR; LGK4; SB0; MM(afB, 1);

            RD_A(afB, 1, 3);
            BAR; LGK4; SB0; MM(afA, 2);

            LGK0; SB0; MM(afB, 3);
        }

        // ---- epilogue: plain stores (L2 write-combining, R13-verified) ----
        float* Cw = C + (size_t)(by * BM + wm * 128 + kgrp * 4) * N
                    + (size_t)(bx * BN + wn * 64 + mrow);
#pragma unroll
        for (int mi = 0; mi < 8; ++mi)
#pragma unroll
            for (int ni = 0; ni < 4; ++ni)
#pragma unroll
                for (int r = 0; r < 4; ++r)
                    Cw[(size_t)(mi * 16 + r) * N + ni * 16] = acc[mi][ni][r];
    }
}

// ============ safety-net fallback if ws is too small (slow but correct) ============
__global__ void gemm_naive(const float* __restrict__ x, const int* __restrict__ W,
                           float* __restrict__ out) {
    int n = blockIdx.x * blockDim.x + threadIdx.x;
    int t = blockIdx.y;
    const float* xr = x + (size_t)t * DIN;
    float acc = 0.f;
    for (int k = 0; k < DIN; ++k)
        acc += xr[k] * (float)W[(size_t)k * DOUT + n];
    out[(size_t)t * DOUT + n] = acc;
}

extern "C" void kernel_launch(void* const* d_in, const int* in_sizes, int n_in,
                              void* d_out, int out_size, void* d_ws, size_t ws_size,
                              hipStream_t stream) {
    const float* x = (const float*)d_in[0];
    const int*   W = (const int*)d_in[1];
    float* out = (float*)d_out;

    const size_t xb_elems = (size_t)TOKENS * DIN;           // 64 MB bf16
    const size_t wt_elems = (size_t)DIN * DOUT;             // 32 MB bf16
    const size_t need = (xb_elems + wt_elems) * sizeof(unsigned short);

    if (ws_size < need) {   // should not happen; correctness safety net
        dim3 g(DOUT / 256, TOKENS);
        gemm_naive<<<g, 256, 0, stream>>>(x, W, out);
        return;
    }

    unsigned short* xb = (unsigned short*)d_ws;
    unsigned short* Wt = xb + xb_elems;

    void* args[] = { (void*)&x, (void*)&W, (void*)&xb, (void*)&Wt, (void*)&out };
    hipLaunchCooperativeKernel((const void*)gemm_fused, dim3(256), dim3(512),
                               args, 0, stream);
}

// Round 17
// 467.950 us; speedup vs baseline: 1.3582x; 1.3582x over previous
//
#include <hip/hip_runtime.h>
#include <stdint.h>

// Problem dims (fixed by reference)
#define TOKENS 8192
#define DIN    4096
#define DOUT   4096

typedef short bf16x8 __attribute__((ext_vector_type(8)));  // 8 bf16 = 4 VGPRs
typedef float f32x4  __attribute__((ext_vector_type(4)));  // MFMA 16x16 accum
typedef int   i32x4  __attribute__((ext_vector_type(4)));  // NT-loadable int4
typedef float f32x4v __attribute__((ext_vector_type(4)));  // NT-loadable float4

// ---- fp32 -> bf16 round-to-nearest-even (inputs finite) ----
__device__ __forceinline__ unsigned short f2bf(float f) {
    union { float f; unsigned int u; } v; v.f = f;
    return (unsigned short)((v.u + 0x7fffu + ((v.u >> 16) & 1u)) >> 16);
}

// ---- ternary int {-1,0,1} -> bf16 bit pattern (2 selects, no float math) ----
__device__ __forceinline__ unsigned short tern2bf(int v) {
    return v == 0 ? (unsigned short)0u
                  : (v > 0 ? (unsigned short)0x3F80u : (unsigned short)0xBF80u);
}

// ---- async global->LDS, 16B/lane; LDS dest = wave-uniform base + lane*16 ----
__device__ __forceinline__ void gload_lds16(const unsigned short* g, unsigned short* l) {
    __builtin_amdgcn_global_load_lds(
        (const __attribute__((address_space(1))) unsigned int*)g,
        (__attribute__((address_space(3))) unsigned int*)l,
        16, 0, 0);
}

// ================= fused prologue (R9-verified): one kernel, two jobs =================
// Measured at its BW floor (~50 us): R16's single-dispatch experiment proved the
// ~175 us total-minus-dispatch residual is fixed harness overhead, not this kernel.
#define WBLKS 1024
#define XBLKS 2048

__global__ __launch_bounds__(256) void fused_cvt(
    const float* __restrict__ x, const int* __restrict__ W,
    unsigned short* __restrict__ xb, unsigned short* __restrict__ Wt) {
    __shared__ unsigned short lds[64][264];   // [n_local][k_local], pitch 264
    const int t = threadIdx.x;

    if (blockIdx.x < WBLKS) {
        // ---- W transpose: tile k0..k0+255 x n0..n0+63 ----
        const int b  = blockIdx.x;
        const int k0 = (b >> 6) * 256;        // 16 k-tiles
        const int n0 = (b & 63) * 64;         // 64 n-tiles
        const int kq = t >> 4;                // 0..15 (k quad group)
        const int nq = t & 15;                // 0..15 (n quad group)
#pragma unroll
        for (int it = 0; it < 4; ++it) {
            const int kb = it * 64 + kq * 4;  // k_local base (4 rows)
            const int* wp = &W[(size_t)(k0 + kb) * DOUT + n0 + nq * 4];
            i32x4 v0 = __builtin_nontemporal_load((const i32x4*)(wp));
            i32x4 v1 = __builtin_nontemporal_load((const i32x4*)(wp + DOUT));
            i32x4 v2 = __builtin_nontemporal_load((const i32x4*)(wp + 2 * DOUT));
            i32x4 v3 = __builtin_nontemporal_load((const i32x4*)(wp + 3 * DOUT));
            uint2 p;
            p.x = (unsigned)tern2bf(v0.x) | ((unsigned)tern2bf(v1.x) << 16);
            p.y = (unsigned)tern2bf(v2.x) | ((unsigned)tern2bf(v3.x) << 16);
            *(uint2*)&lds[nq * 4 + 0][kb] = p;
            p.x = (unsigned)tern2bf(v0.y) | ((unsigned)tern2bf(v1.y) << 16);
            p.y = (unsigned)tern2bf(v2.y) | ((unsigned)tern2bf(v3.y) << 16);
            *(uint2*)&lds[nq * 4 + 1][kb] = p;
            p.x = (unsigned)tern2bf(v0.z) | ((unsigned)tern2bf(v1.z) << 16);
            p.y = (unsigned)tern2bf(v2.z) | ((unsigned)tern2bf(v3.z) << 16);
            *(uint2*)&lds[nq * 4 + 2][kb] = p;
            p.x = (unsigned)tern2bf(v0.w) | ((unsigned)tern2bf(v1.w) << 16);
            p.y = (unsigned)tern2bf(v2.w) | ((unsigned)tern2bf(v3.w) << 16);
            *(uint2*)&lds[nq * 4 + 3][kb] = p;
        }
        __syncthreads();
        const int n = t >> 2;                 // 0..63
        const int s = t & 3;
        unsigned short* drow = Wt + (size_t)(n0 + n) * DIN + k0;
#pragma unroll
        for (int u = 0; u < 8; ++u) {
            const int k = u * 32 + s * 8;     // lanes 0-3 cover 64B contiguous
            *(uint4*)&drow[k] = *(const uint4*)&lds[n][k];
        }
    } else {
        // ---- x convert part: 8 chunks of 8 floats per thread ----
        const int b2 = blockIdx.x - WBLKS;    // 0..2047
        const int stride = XBLKS * 256;       // chunks per sweep
        int c = b2 * 256 + t;
        const f32x4v* x4 = (const f32x4v*)x;
        uint4* o = (uint4*)xb;                // 8 bf16 = 16B per chunk
#pragma unroll
        for (int j = 0; j < 8; ++j, c += stride) {
            f32x4v a = __builtin_nontemporal_load(&x4[2 * c]);
            f32x4v bvec = __builtin_nontemporal_load(&x4[2 * c + 1]);
            uint4 p;
            p.x = (unsigned)f2bf(a.x)    | ((unsigned)f2bf(a.y) << 16);
            p.y = (unsigned)f2bf(a.z)    | ((unsigned)f2bf(a.w) << 16);
            p.z = (unsigned)f2bf(bvec.x) | ((unsigned)f2bf(bvec.y) << 16);
            p.w = (unsigned)f2bf(bvec.z) | ((unsigned)f2bf(bvec.w) << 16);
            o[c] = p;
        }
    }
}

// ========= main GEMM: 256x256, BK=64, 1-barrier/phase pipeline (SESSION BEST) =========
// R13: 238.8 us, MfmaUtil 48%, 0 bank conflicts, WRITE_SIZE 131 MB (1152 TF).
// Phase: [reads (next-phase A-quad; +B-burst at p0/p4)] [stage half-tile]
//        [VM2 at p2/p6] BAR LGK4 SB0 setprio(1) 16xMFMA setprio(0)
// Stage ledger per iter (tiles t0=buf0@kt, t1=buf1@kt+64):
//   p0/p1: A@kt+64 -> sA[1]     p2/p3: B@kt+128 -> sB[0]
//   p4/p5: A@kt+128 -> sA[0]    p6/p7: B@kt+192 -> sB[1]
// VM2@p2: confirms leftover B1 + A@kt+64 cross-wave before p3's sA[1] read.
// VM2@p6: confirms B@kt+128 + A@kt+128 before p7/next-p0 reads. Never 0 in loop.
// WAR: last reads of a buffer drain via LGK4 before the barrier preceding the
// overwriting stage issue. LGK4 = "all but my 4 newest" (in-order DS) = this
// phase's MFMA operands complete; B-burst pinned before A-reads by SB0.
// Refuted alternatives (this session): 16-barrier m201 port (264), read-ahead
// lgkm variants (265), TLP 128x256/BK32 (292), A-from-global (636), 32x32 MFMA
// (269, conflicts), 4-phase merges (261/243), NT C-stores (255), coop fusion (460).
#define BM 256
#define BN 256
#define BK 64

#define STAGE_A(bufi, h, kt)                                                \
    do {                                                                    \
        gload_lds16(gA + (size_t)((h) * 128) * DIN + (kt),                  \
                    &sA[bufi][(h) * 8192 + wave * 1024]);                   \
        gload_lds16(gA + (size_t)((h) * 128 + 8) * DIN + (kt),              \
                    &sA[bufi][(h) * 8192 + wave * 1024 + 512]);             \
    } while (0)

#define STAGE_B(bufi, h, kt)                                                \
    do {                                                                    \
        gload_lds16(gB + (size_t)((h) * 128) * DIN + (kt),                  \
                    &sB[bufi][(h) * 8192 + wave * 1024]);                   \
        gload_lds16(gB + (size_t)((h) * 128 + 8) * DIN + (kt),              \
                    &sB[bufi][(h) * 8192 + wave * 1024 + 512]);             \
    } while (0)

#define BAR  __builtin_amdgcn_s_barrier()
#define SB0  __builtin_amdgcn_sched_barrier(0)
#define VM4  asm volatile("s_waitcnt vmcnt(4)" ::: "memory")
#define VM2  asm volatile("s_waitcnt vmcnt(2)" ::: "memory")
#define VM0  asm volatile("s_waitcnt vmcnt(0)" ::: "memory")
#define LGK4 asm volatile("s_waitcnt lgkmcnt(4)" ::: "memory")
#define LGK0 asm volatile("s_waitcnt lgkmcnt(0)" ::: "memory")

// 8 ds_read_b128: all B-frags of LDS buffer BUF (resident across 4 phases)
#define RD_B(BUF)                                                           \
    do {                                                                    \
        _Pragma("unroll") for (int ni = 0; ni < 4; ++ni) {                  \
            bfr[ni][0] = *(const bf16x8*)&sB[BUF][rowB + ni * 1024 + q80];  \
            bfr[ni][1] = *(const bf16x8*)&sB[BUF][rowB + ni * 1024 + q81];  \
        }                                                                   \
    } while (0)

// 4 ds_read_b128: A-frags, quadrant QD of buffer BUF -> register set AF
#define RD_A(AF, BUF, QD)                                                   \
    do {                                                                    \
        _Pragma("unroll") for (int m2 = 0; m2 < 2; ++m2) {                  \
            AF[m2][0] =                                                     \
                *(const bf16x8*)&sA[BUF][rowA + ((QD)*2 + m2) * 1024 + q80];\
            AF[m2][1] =                                                     \
                *(const bf16x8*)&sA[BUF][rowA + ((QD)*2 + m2) * 1024 + q81];\
        }                                                                   \
    } while (0)

// 16 MFMA: quadrant QD from A-set AF + resident bfr
#define MM(AF, QD)                                                          \
    do {                                                                    \
        __builtin_amdgcn_s_setprio(1);                                      \
        _Pragma("unroll") for (int ks = 0; ks < 2; ++ks)                    \
            _Pragma("unroll") for (int m2 = 0; m2 < 2; ++m2)                \
                _Pragma("unroll") for (int ni = 0; ni < 4; ++ni)            \
                    acc[(QD)*2 + m2][ni] =                                  \
                        __builtin_amdgcn_mfma_f32_16x16x32_bf16(            \
                            AF[m2][ks], bfr[ni][ks],                        \
                            acc[(QD)*2 + m2][ni], 0, 0, 0);                 \
        __builtin_amdgcn_s_setprio(0);                                      \
    } while (0)

__global__ __launch_bounds__(512, 2) void gemm_bt(
    const unsigned short* __restrict__ A,   // [M][K] bf16
    const unsigned short* __restrict__ B,   // [N][K] bf16 (W transposed)
    float* __restrict__ C) {                // [M][N] fp32
    const int K = DIN, N = DOUT;

    __shared__ __align__(16) unsigned short sA[2][BM * BK];  // 2 x 32 KB
    __shared__ __align__(16) unsigned short sB[2][BN * BK];  // 2 x 32 KB

    const int tid  = threadIdx.x;
    const int wave = tid >> 6;
    const int lane = tid & 63;
    const int wm = wave >> 2;               // 0..1  (M)
    const int wn = wave & 3;                // 0..3  (N)

    // ---- T1: XCD-aware bijective block swizzle (512 wgs, 8 XCDs, 64/XCD) ----
    const int wg  = blockIdx.x + gridDim.x * blockIdx.y;   // hardware linear id
    const int xcd = wg & 7;
    const int idx = wg >> 3;                               // 0..63 within XCD
    const int bx  = (xcd & 1) * 8 + (idx & 7);             // 0..15  (N tiles)
    const int by  = (xcd >> 1) * 8 + (idx >> 3);           // 0..31  (M tiles)

    // ---- staging addressing: wave w stages rows 16w..16w+15 of each half ----
    const int lrow = lane >> 3;             // 0..7 row within 8-row chunk
    const int qsrc = (lane & 7) ^ lrow;     // pre-swizzled global k-quad
    const unsigned short* gA =
        A + (size_t)(by * BM + wave * 16 + lrow) * K + qsrc * 8;
    const unsigned short* gB =
        B + (size_t)(bx * BN + wave * 16 + lrow) * K + qsrc * 8;

    // ---- fragment read addressing (swizzled ds_read) ----
    const int mrow = lane & 15;
    const int kgrp = lane >> 4;             // 0..3
    const int xr   = lane & 7;              // = row&7 of the frag row
    const int q80  = ((kgrp ^ xr) << 3);        // ks=0 swizzled quad * 8
    const int q81  = (((4 | kgrp) ^ xr) << 3);  // ks=1
    const int rowA = (wm * 128 + mrow) << 6;    // *64 elems/row
    const int rowB = (wn * 64 + mrow) << 6;

    f32x4 acc[8][4];
#pragma unroll
    for (int i = 0; i < 8; ++i)
#pragma unroll
        for (int j = 0; j < 4; ++j) {
            f32x4 z = {0.f, 0.f, 0.f, 0.f};
            acc[i][j] = z;
        }
    bf16x8 bfr[4][2];     // B-frags: resident across a K-tile's 4 phases
    bf16x8 afA[2][2];     // A-frag ping
    bf16x8 afB[2][2];     // A-frag pong

    // ---- prologue: A0, B0, B1 (12 gloads); VM4 confirms A0,B0; B1 flies ----
    STAGE_A(0, 0, 0);
    STAGE_A(0, 1, 0);
    STAGE_B(0, 0, 0);
    STAGE_B(0, 1, 0);
    STAGE_B(1, 0, 64);
    STAGE_B(1, 1, 64);
    VM4;
    BAR;
    RD_A(afA, 0, 0);      // tile0 Q0 (consumed at first p0)

    // ---- main loop: 31 iters (tiles 0..61), 8 phases, 1 barrier each ----
    for (int kt = 0; kt + 256 <= K; kt += 128) {
        // p0: B0-burst (pinned first) + A0Q1 ahead; MFMA Q0(buf0)
        RD_B(0); SB0; RD_A(afB, 0, 1);
        STAGE_A(1, 0, kt + 64);
        BAR; LGK4; SB0; MM(afA, 0);
        // p1
        RD_A(afA, 0, 2);
        STAGE_A(1, 1, kt + 64);
        BAR; LGK4; SB0; MM(afB, 1);
        // p2: VM2 confirms leftover B1 + A@kt+64 before BAR (p3 reads sA[1])
        RD_A(afB, 0, 3);
        STAGE_B(0, 0, kt + 128);
        VM2;
        BAR; LGK4; SB0; MM(afA, 2);
        // p3
        RD_A(afA, 1, 0);
        STAGE_B(0, 1, kt + 128);
        BAR; LGK4; SB0; MM(afB, 3);
        // p4: B1-burst + A1Q1; MFMA Q0(buf1)
        RD_B(1); SB0; RD_A(afB, 1, 1);
        STAGE_A(0, 0, kt + 128);
        BAR; LGK4; SB0; MM(afA, 0);
        // p5
        RD_A(afA, 1, 2);
        STAGE_A(0, 1, kt + 128);
        BAR; LGK4; SB0; MM(afB, 1);
        // p6: VM2 confirms B@kt+128 + A@kt+128 before BAR (p7/next-p0 reads)
        RD_A(afB, 1, 3);
        STAGE_B(1, 0, kt + 192);
        VM2;
        BAR; LGK4; SB0; MM(afA, 2);
        // p7: read next tile0's Q0 from re-staged sA[0]
        RD_A(afA, 0, 0);
        STAGE_B(1, 1, kt + 192);
        BAR; LGK4; SB0; MM(afB, 3);
    }

    // ---- peeled tail: tiles 62 (buf0) and 63 (buf1) ----
    {
        RD_B(0); SB0; RD_A(afB, 0, 1);
        STAGE_A(1, 0, K - 64);
        BAR; LGK4; SB0; MM(afA, 0);

        RD_A(afA, 0, 2);
        STAGE_A(1, 1, K - 64);
        BAR; LGK4; SB0; MM(afB, 1);

        RD_A(afB, 0, 3);
        VM0;              // confirm B63 + A63 fully; no more stages
        BAR; LGK4; SB0; MM(afA, 2);

        RD_A(afA, 1, 0);
        BAR; LGK4; SB0; MM(afB, 3);

        RD_B(1); SB0; RD_A(afB, 1, 1);
        BAR; LGK4; SB0; MM(afA, 0);

        RD_A(afA, 1, 2);
        BAR; LGK4; SB0; MM(afB, 1);

        RD_A(afB, 1, 3);
        BAR; LGK4; SB0; MM(afA, 2);

        LGK0; SB0; MM(afB, 3);
    }

    // ---- epilogue: C/D layout col=lane&15, row=(lane>>4)*4+reg ----
    // Plain stores (R13-verified WIN): L2 write-combines 64B halves into 128B
    // lines (NT stores bypassed combining: 170 MB writes, +16 us).
    float* Cw = C + (size_t)(by * BM + wm * 128 + kgrp * 4) * N
                + (size_t)(bx * BN + wn * 64 + mrow);
#pragma unroll
    for (int mi = 0; mi < 8; ++mi)
#pragma unroll
        for (int ni = 0; ni < 4; ++ni)
#pragma unroll
            for (int r = 0; r < 4; ++r)
                Cw[(size_t)(mi * 16 + r) * N + ni * 16] = acc[mi][ni][r];
}

// ============ safety-net fallback if ws is too small (slow but correct) ============
__global__ void gemm_naive(const float* __restrict__ x, const int* __restrict__ W,
                           float* __restrict__ out) {
    int n = blockIdx.x * blockDim.x + threadIdx.x;
    int t = blockIdx.y;
    const float* xr = x + (size_t)t * DIN;
    float acc = 0.f;
    for (int k = 0; k < DIN; ++k)
        acc += xr[k] * (float)W[(size_t)k * DOUT + n];
    out[(size_t)t * DOUT + n] = acc;
}

extern "C" void kernel_launch(void* const* d_in, const int* in_sizes, int n_in,
                              void* d_out, int out_size, void* d_ws, size_t ws_size,
                              hipStream_t stream) {
    const float* x = (const float*)d_in[0];
    const int*   W = (const int*)d_in[1];
    float* out = (float*)d_out;

    const size_t xb_elems = (size_t)TOKENS * DIN;           // 64 MB bf16
    const size_t wt_elems = (size_t)DIN * DOUT;             // 32 MB bf16
    const size_t need = (xb_elems + wt_elems) * sizeof(unsigned short);

    if (ws_size < need) {   // should not happen; correctness safety net
        dim3 g(DOUT / 256, TOKENS);
        gemm_naive<<<g, 256, 0, stream>>>(x, W, out);
        return;
    }

    unsigned short* xb = (unsigned short*)d_ws;
    unsigned short* Wt = xb + xb_elems;

    fused_cvt<<<WBLKS + XBLKS, 256, 0, stream>>>(x, W, xb, Wt);

    dim3 grid(DOUT / BN, TOKENS / BM);   // (16, 32)
    gemm_bt<<<grid, 512, 0, stream>>>(xb, Wt, out);
}